// Round 12
// baseline (297.482 us; speedup 1.0000x reference)
//
#include <hip/hip_runtime.h>

#define NB 4
#define SEQ 4096
#define DIMK 1024
#define DKV 128
#define SCALE 0.08838834764831845f   // 1/sqrt(128)

typedef float  f32x4  __attribute__((ext_vector_type(4)));
typedef float  f32x16 __attribute__((ext_vector_type(16)));
typedef _Float16 f16x8 __attribute__((ext_vector_type(8)));

static __device__ __forceinline__ int pkrtz(float a, float b) {
    auto h = __builtin_amdgcn_cvt_pkrtz(a, b);   // __fp16 ext_vector(2)
    return __builtin_bit_cast(int, h);
}

// ---------------- kernel 0: transpose W -> f16 WT[3][128][1024] ----------------
__global__ void prep_wt(const float* __restrict__ Wq, const float* __restrict__ Wk,
                        const float* __restrict__ Wv, _Float16* __restrict__ WT) {
    int tid = blockIdx.x * 256 + threadIdx.x;
    int n  = tid & 127;
    int k  = (tid >> 7) & 1023;
    int w3 = tid >> 17;
    const float* W = (w3 == 0) ? Wq : (w3 == 1) ? Wk : Wv;
    WT[((size_t)w3 * 128 + n) * 1024 + k] = (_Float16)W[(size_t)k * 128 + n];
}

// ---------------- kernel 1: QKV projection (r10 proven: LDS-staged W, X prefetch) ----------------
// NOTE r11 lesson: direct W-fragment reads 4x the per-CU L2 traffic (no cross-wave
// amortization) and cost +60us. LDS staging here is a bandwidth amortizer, keep it.
__global__ __launch_bounds__(256) void qkv_proj(
    const float* __restrict__ X,
    const float* __restrict__ bq, const float* __restrict__ bk, const float* __restrict__ bv,
    const _Float16* __restrict__ WT,
    _Float16* __restrict__ Qh, _Float16* __restrict__ Kh, _Float16* __restrict__ VTh) {

    __shared__ __attribute__((aligned(16))) _Float16 WTs[128 * 40];
    const int t = threadIdx.x;
    const int w = t >> 6, l = t & 63;
    const int lrow = l & 15, lg = l >> 4;
    const int w3   = blockIdx.x % 3;
    const int tile = blockIdx.x / 3;
    const int r0 = tile * 64;

    f32x4 acc[8] = {};
    const float* xrow = X + (size_t)(r0 + w * 16 + lrow) * DIMK;
    const _Float16* Wbase = WT + (size_t)w3 * 128 * 1024;

    float4 xc0 = *(const float4*)(xrow + lg * 8);
    float4 xc1 = *(const float4*)(xrow + lg * 8 + 4);

    for (int k0 = 0; k0 < DIMK; k0 += 32) {
        __syncthreads();
        #pragma unroll
        for (int i = 0; i < 2; ++i) {
            int c = t + 256 * i;
            int row = c >> 2, part = c & 3;
            *(int4*)((char*)WTs + row * 80 + part * 16) =
                *(const int4*)(Wbase + (size_t)row * 1024 + k0 + part * 8);
        }
        float4 xn0, xn1;
        if (k0 + 32 < DIMK) {
            xn0 = *(const float4*)(xrow + k0 + 32 + lg * 8);
            xn1 = *(const float4*)(xrow + k0 + 32 + lg * 8 + 4);
        }
        __syncthreads();
        f16x8 a;
        a[0] = (_Float16)xc0.x; a[1] = (_Float16)xc0.y; a[2] = (_Float16)xc0.z; a[3] = (_Float16)xc0.w;
        a[4] = (_Float16)xc1.x; a[5] = (_Float16)xc1.y; a[6] = (_Float16)xc1.z; a[7] = (_Float16)xc1.w;

        #pragma unroll
        for (int n = 0; n < 8; ++n) {
            f16x8 bf = *(const f16x8*)((const char*)WTs + (n * 16 + lrow) * 80 + lg * 16);
            acc[n] = __builtin_amdgcn_mfma_f32_16x16x32_f16(a, bf, acc[n], 0, 0, 0);
        }
        xc0 = xn0; xc1 = xn1;
    }
    const float* bias = (w3 == 0) ? bq : (w3 == 1) ? bk : bv;
    #pragma unroll
    for (int n = 0; n < 8; ++n) {
        int col = n * 16 + lrow;
        float bv_ = bias[col];
        #pragma unroll
        for (int j = 0; j < 4; ++j) {
            int grow = r0 + w * 16 + lg * 4 + j;
            float val = acc[n][j] + bv_;
            if (w3 == 0) {
                Qh[(size_t)grow * DKV + col] = (_Float16)(val * SCALE);
            } else if (w3 == 1) {
                Kh[(size_t)grow * DKV + col] = (_Float16)val;
            } else {
                int b = grow >> 12, sp = grow & 4095;
                VTh[((size_t)b * DKV + col) * SEQ + sp] = (_Float16)val;
            }
        }
    }
}

// ---------------- kernel 2: flash attention, 4 kv-groups x 2 dv-halves ----------------
// grid 512 (XCD-swizzled), block 512 thr = 8 waves. Group g (2 waves) owns keys
// [g*1024,(g+1)*1024), KVBLK=32; within a group wave wh owns dv-half [wh*64,(wh+1)*64).
// K tile (8KB/group) staged cooperatively -> LDS 32KB; V prefetched DIRECT to regs
// (issued between barriers, consumed after QK^T+softmax -> latency hidden; r11's
// mistake was in-chain loads). QK^T duplicated per dv-half (MFMA is cheap, 4% cyc).
// K swizzle (row&15)<<4: 32 rows -> 16 slots -> 2-way aliasing = free (m136).
// __launch_bounds__(512,4): VGPR cap 128, est ~112 live -> 16 waves/CU (2 blocks).
__global__ __launch_bounds__(512, 4) void attn_kernel(
    const _Float16* __restrict__ Qh, const _Float16* __restrict__ Kh,
    const _Float16* __restrict__ VTh, float* __restrict__ out) {

    __shared__ __attribute__((aligned(16))) char lds[33280];

    const int t = threadIdx.x;
    const int l = t & 63;
    const int lq = l & 31;          // q column within tile
    const int hi = l >> 5;
    const int g  = t >> 7;          // kv group 0..3
    const int wh = (t >> 6) & 1;    // dv half 0..1
    const int lt = t & 127;         // thread within group (2 waves stage together)

    // XCD-chunked swizzle over 512 blocks
    const int work = (blockIdx.x & 7) * 64 + (blockIdx.x >> 3);
    const int b  = work >> 7;            // 128 q-tiles per batch
    const int qt = work & 127;
    const int q0 = qt * 32;

    char* Kg = lds + g * 8192;           // [32 k][128 dk] f16, rows 256B, XOR (row&15)<<4

    // Q fragments (B-layout): qf[c] = Q[q0+lq][c*16 + hi*8 .. +8]
    f16x8 qf[8];
    #pragma unroll
    for (int c = 0; c < 8; ++c)
        qf[c] = *(const f16x8*)(Qh + (size_t)(b * SEQ + q0 + lq) * DKV + c * 16 + hi * 8);

    f32x16 o[2] = {};                    // O^T: 2 dv-tiles of 32 (this wave's dv-half)
    float m = -INFINITY, lsum = 0.f;

    const _Float16* Vbase = VTh + ((size_t)b * DKV + wh * 64 + lq) * SEQ + hi * 8;

    for (int kt = 0; kt < 32; ++kt) {
        const int k0 = g * 1024 + kt * 32;
        __syncthreads();                 // everyone done reading previous K tile
        // stage K tile 32x128 f16 (group-cooperative: 128 lanes x 4 chunks)
        #pragma unroll
        for (int i = 0; i < 4; ++i) {
            int c = lt + 128 * i; int row = c >> 4, part = c & 15;
            *(int4*)(Kg + row * 256 + ((part * 16) ^ ((row & 15) << 4))) =
                *(const int4*)(Kh + (size_t)(b * SEQ + k0 + row) * DKV + part * 8);
        }
        // V prefetch direct to regs (consumed after QK^T+softmax -> latency hidden)
        f16x8 vreg[4];
        #pragma unroll
        for (int s_ = 0; s_ < 2; ++s_)
            #pragma unroll
            for (int dvt = 0; dvt < 2; ++dvt)
                vreg[s_ * 2 + dvt] = *(const f16x8*)(Vbase + (size_t)(dvt * 32) * SEQ +
                                                     k0 + s_ * 16);
        __syncthreads();                 // K tile visible

        // ---- S^T = K Q^T : one 32x32 tile, K=128 via 8 chained MFMAs ----
        f32x16 s = {};
        #pragma unroll
        for (int c = 0; c < 8; ++c) {
            f16x8 kf = *(const f16x8*)(Kg + lq * 256 +
                                       (((2 * c + hi) * 16) ^ ((lq & 15) << 4)));
            s = __builtin_amdgcn_mfma_f32_32x32x16_f16(kf, qf[c], s, 0, 0, 0);
        }

        // ---- in-register online softmax ----
        float tm = -INFINITY;
        #pragma unroll
        for (int r = 0; r < 16; ++r) tm = fmaxf(tm, s[r]);
        tm = fmaxf(tm, __shfl_xor(tm, 32));

        if (__any(tm > m + 8.f)) {           // defer-max (T13)
            float mnew = fmaxf(m, tm);
            float corr = __expf(m - mnew);
            m = mnew;
            lsum *= corr;
            o[0] *= corr;
            o[1] *= corr;
        }
        float ts = 0.f;
        #pragma unroll
        for (int r = 0; r < 16; ++r) { s[r] = __expf(s[r] - m); ts += s[r]; }
        ts += __shfl_xor(ts, 32);
        lsum += ts;

        // ---- pack P to f16 (T12): wv[i] = (p[reg 2i], p[reg 2i+1]) ----
        int wv[8];
        #pragma unroll
        for (int i = 0; i < 8; ++i) wv[i] = pkrtz(s[2 * i], s[2 * i + 1]);

        // ---- O^T += V^T P : 2 k-slices x 2 dv-tiles, V from prefetched regs ----
        #pragma unroll
        for (int s_ = 0; s_ < 2; ++s_) {
            const int base = s_ * 4;
            int x0 = __shfl_xor(wv[base + 0], 32);
            int x1 = __shfl_xor(wv[base + 1], 32);
            int x2 = __shfl_xor(wv[base + 2], 32);
            int x3 = __shfl_xor(wv[base + 3], 32);
            union { int i[4]; f16x8 v; } bu;
            bu.i[0] = hi ? x2 : wv[base + 0];
            bu.i[1] = hi ? x3 : wv[base + 1];
            bu.i[2] = hi ? wv[base + 2] : x0;
            bu.i[3] = hi ? wv[base + 3] : x1;
            #pragma unroll
            for (int dvt = 0; dvt < 2; ++dvt)
                o[dvt] = __builtin_amdgcn_mfma_f32_32x32x16_f16(vreg[s_ * 2 + dvt], bu.v,
                                                                o[dvt], 0, 0, 0);
        }
    }

    // -------- 2-round tree merge over kv-groups (per dv-half), then transpose+store ----
    float* obuf  = (float*)lds;                 // 4 snapshots x 2048 f32 = 32 KB
    float* mlbuf = (float*)(lds + 32768);       // 2 snapshots x 64 f32

    __syncthreads();
    if (g == 1 || g == 3) {                     // round A publish
        int sb = (g == 3);
        #pragma unroll
        for (int dvt = 0; dvt < 2; ++dvt)
            #pragma unroll
            for (int r = 0; r < 16; ++r)
                obuf[(sb * 2 + wh) * 2048 + (dvt * 16 + r) * 64 + l] = o[dvt][r];
        if (wh == 0 && l < 32) {
            mlbuf[sb * 64 + l * 2 + 0] = m;
            mlbuf[sb * 64 + l * 2 + 1] = lsum;
        }
    }
    __syncthreads();
    if (g == 0 || g == 2) {                     // round A merge
        int sb = (g == 2);
        float mo  = mlbuf[sb * 64 + lq * 2 + 0];
        float lo_ = mlbuf[sb * 64 + lq * 2 + 1];
        float mn = fmaxf(m, mo);
        float ca = __expf(m - mn);
        float cb = __expf(mo - mn);
        m = mn;
        lsum = lsum * ca + lo_ * cb;
        #pragma unroll
        for (int dvt = 0; dvt < 2; ++dvt)
            #pragma unroll
            for (int r = 0; r < 16; ++r)
                o[dvt][r] = o[dvt][r] * ca +
                            obuf[(sb * 2 + wh) * 2048 + (dvt * 16 + r) * 64 + l] * cb;
    }
    __syncthreads();
    if (g == 2) {                               // round B publish (slots 0,1 now free)
        #pragma unroll
        for (int dvt = 0; dvt < 2; ++dvt)
            #pragma unroll
            for (int r = 0; r < 16; ++r)
                obuf[wh * 2048 + (dvt * 16 + r) * 64 + l] = o[dvt][r];
        if (wh == 0 && l < 32) {
            mlbuf[l * 2 + 0] = m;
            mlbuf[l * 2 + 1] = lsum;
        }
    }
    __syncthreads();
    if (g == 0) {                               // final merge + normalize
        float mo  = mlbuf[lq * 2 + 0];
        float lo_ = mlbuf[lq * 2 + 1];
        float mn = fmaxf(m, mo);
        float ca = __expf(m - mn);
        float cb = __expf(mo - mn);
        float rl = 1.0f / (lsum * ca + lo_ * cb);
        #pragma unroll
        for (int dvt = 0; dvt < 2; ++dvt)
            #pragma unroll
            for (int r = 0; r < 16; ++r)
                o[dvt][r] = (o[dvt][r] * ca +
                             obuf[wh * 2048 + (dvt * 16 + r) * 64 + l] * cb) * rl;
    }
    __syncthreads();
    // transpose O^T -> row-major via LDS
    float* tbuf = (float*)lds;                  // [32][132] f32 = 16896 B
    if (g == 0) {
        #pragma unroll
        for (int dvt = 0; dvt < 2; ++dvt)
            #pragma unroll
            for (int r = 0; r < 16; ++r) {
                int dv = wh * 64 + dvt * 32 + (r & 3) + 8 * (r >> 2) + 4 * hi;
                tbuf[lq * 132 + dv] = o[dvt][r];
            }
    }
    __syncthreads();
    const size_t obase = (size_t)(b * SEQ + qt * 32) * DKV;
    int row = t >> 4, c0 = (t & 15) * 8;
    float4 v0 = *(const float4*)(tbuf + row * 132 + c0);
    float4 v1 = *(const float4*)(tbuf + row * 132 + c0 + 4);
    *(float4*)(out + obase + row * 128 + c0)     = v0;
    *(float4*)(out + obase + row * 128 + c0 + 4) = v1;
}

extern "C" void kernel_launch(void* const* d_in, const int* in_sizes, int n_in,
                              void* d_out, int out_size, void* d_ws, size_t ws_size,
                              hipStream_t stream) {
    const float* X  = (const float*)d_in[0];
    const float* Wq = (const float*)d_in[1];
    const float* bq = (const float*)d_in[2];
    const float* Wk = (const float*)d_in[3];
    const float* bk = (const float*)d_in[4];
    const float* Wv = (const float*)d_in[5];
    const float* bv = (const float*)d_in[6];
    float* out = (float*)d_out;

    const size_t nqe = (size_t)NB * SEQ * DKV;            // 2M elements
    _Float16* Qh  = (_Float16*)d_ws;
    _Float16* Kh  = Qh  + nqe;
    _Float16* VTh = Kh  + nqe;
    _Float16* WTh = VTh + nqe;                            // 3*128*1024 f16

    prep_wt<<<(3 * 1024 * 128) / 256, 256, 0, stream>>>(Wq, Wk, Wv, WTh);
    qkv_proj<<<(NB * SEQ / 64) * 3, 256, 0, stream>>>(X, bq, bk, bv, WTh, Qh, Kh, VTh);
    attn_kernel<<<NB * 128, 512, 0, stream>>>(Qh, Kh, VTh, out);
}

// Round 13
// 137.979 us; speedup vs baseline: 2.1560x; 2.1560x over previous
//
#include <hip/hip_runtime.h>

#define NB 4
#define SEQ 4096
#define DIMK 1024
#define DKV 128
#define SCALE 0.08838834764831845f      // 1/sqrt(128)
#define QSCALE 0.1275174272f            // SCALE * log2(e): softmax runs in exp2 domain

typedef float  f32x4  __attribute__((ext_vector_type(4)));
typedef float  f32x16 __attribute__((ext_vector_type(16)));
typedef _Float16 f16x8 __attribute__((ext_vector_type(8)));

static __device__ __forceinline__ int pkrtz(float a, float b) {
    auto h = __builtin_amdgcn_cvt_pkrtz(a, b);   // __fp16 ext_vector(2)
    return __builtin_bit_cast(int, h);
}

// ---------------- kernel 0: transpose W -> f16 WT[3][128][1024] ----------------
__global__ void prep_wt(const float* __restrict__ Wq, const float* __restrict__ Wk,
                        const float* __restrict__ Wv, _Float16* __restrict__ WT) {
    int tid = blockIdx.x * 256 + threadIdx.x;
    int n  = tid & 127;
    int k  = (tid >> 7) & 1023;
    int w3 = tid >> 17;
    const float* W = (w3 == 0) ? Wq : (w3 == 1) ? Wk : Wv;
    WT[((size_t)w3 * 128 + n) * 1024 + k] = (_Float16)W[(size_t)k * 128 + n];
}

// ---------------- kernel 1: QKV projection (r10 proven; Q pre-scaled by log2e) ----------------
__global__ __launch_bounds__(256) void qkv_proj(
    const float* __restrict__ X,
    const float* __restrict__ bq, const float* __restrict__ bk, const float* __restrict__ bv,
    const _Float16* __restrict__ WT,
    _Float16* __restrict__ Qh, _Float16* __restrict__ Kh, _Float16* __restrict__ VTh) {

    __shared__ __attribute__((aligned(16))) _Float16 WTs[128 * 40];
    const int t = threadIdx.x;
    const int w = t >> 6, l = t & 63;
    const int lrow = l & 15, lg = l >> 4;
    const int w3   = blockIdx.x % 3;
    const int tile = blockIdx.x / 3;
    const int r0 = tile * 64;

    f32x4 acc[8] = {};
    const float* xrow = X + (size_t)(r0 + w * 16 + lrow) * DIMK;
    const _Float16* Wbase = WT + (size_t)w3 * 128 * 1024;

    float4 xc0 = *(const float4*)(xrow + lg * 8);
    float4 xc1 = *(const float4*)(xrow + lg * 8 + 4);

    for (int k0 = 0; k0 < DIMK; k0 += 32) {
        __syncthreads();
        #pragma unroll
        for (int i = 0; i < 2; ++i) {
            int c = t + 256 * i;
            int row = c >> 2, part = c & 3;
            *(int4*)((char*)WTs + row * 80 + part * 16) =
                *(const int4*)(Wbase + (size_t)row * 1024 + k0 + part * 8);
        }
        float4 xn0, xn1;
        if (k0 + 32 < DIMK) {
            xn0 = *(const float4*)(xrow + k0 + 32 + lg * 8);
            xn1 = *(const float4*)(xrow + k0 + 32 + lg * 8 + 4);
        }
        __syncthreads();
        f16x8 a;
        a[0] = (_Float16)xc0.x; a[1] = (_Float16)xc0.y; a[2] = (_Float16)xc0.z; a[3] = (_Float16)xc0.w;
        a[4] = (_Float16)xc1.x; a[5] = (_Float16)xc1.y; a[6] = (_Float16)xc1.z; a[7] = (_Float16)xc1.w;

        #pragma unroll
        for (int n = 0; n < 8; ++n) {
            f16x8 bf = *(const f16x8*)((const char*)WTs + (n * 16 + lrow) * 80 + lg * 16);
            acc[n] = __builtin_amdgcn_mfma_f32_16x16x32_f16(a, bf, acc[n], 0, 0, 0);
        }
        xc0 = xn0; xc1 = xn1;
    }
    const float* bias = (w3 == 0) ? bq : (w3 == 1) ? bk : bv;
    #pragma unroll
    for (int n = 0; n < 8; ++n) {
        int col = n * 16 + lrow;
        float bv_ = bias[col];
        #pragma unroll
        for (int j = 0; j < 4; ++j) {
            int grow = r0 + w * 16 + lg * 4 + j;
            float val = acc[n][j] + bv_;
            if (w3 == 0) {
                Qh[(size_t)grow * DKV + col] = (_Float16)(val * QSCALE);
            } else if (w3 == 1) {
                Kh[(size_t)grow * DKV + col] = (_Float16)val;
            } else {
                int b = grow >> 12, sp = grow & 4095;
                VTh[((size_t)b * DKV + col) * SEQ + sp] = (_Float16)val;
            }
        }
    }
}

// ---------------- kernel 2: flash attention, wave-private + K-dbuf + V-in-reg ----------------
// grid 512 (XCD-swizzled), block 256 thr = 4 waves; each wave owns 1024 keys, KVBLK=32.
// Pipeline (wave-private, ZERO main-loop barriers):
//   top of iter: issue V(t) loads->regs, K(t+1) loads->regs (latency hides under compute)
//   QK^T from K LDS buf[cur] (written last iter), softmax (exp2 domain), PV from vregs,
//   then ds_write K(t+1) -> buf[cur^1]. Compiler's dep-tracking inserts the waits;
//   they sit off the critical path. K swizzle (row&15): 2-way = free.
// LDS: 4 waves x 2 x 8KB = 64KB -> 2 blocks/CU (8 waves). (256,2) -> VGPR cap 256,
// est ~200 live (r12 lesson: >=512-thr blocks or big min-waves hints clamp to 64 and spill).
__global__ __launch_bounds__(256, 2) void attn_kernel(
    const _Float16* __restrict__ Qh, const _Float16* __restrict__ Kh,
    const _Float16* __restrict__ VTh, float* __restrict__ out) {

    __shared__ __attribute__((aligned(16))) char lds[65536];

    const int t = threadIdx.x;
    const int w = t >> 6, l = t & 63;
    const int lq = l & 31;          // q column within tile
    const int hi = l >> 5;

    // XCD-chunked swizzle over 512 blocks
    const int work = (blockIdx.x & 7) * 64 + (blockIdx.x >> 3);
    const int b  = work >> 7;            // 128 q-tiles per batch
    const int qt = work & 127;
    const int q0 = qt * 32;

    char* bufA = lds + w * 16384;        // K tile buf 0: [32 k][128 dk], rows 256B
    char* bufB = bufA + 8192;            // K tile buf 1

    // Q fragments (B-layout): qf[c] = Q[q0+lq][c*16 + hi*8 .. +8]
    f16x8 qf[8];
    #pragma unroll
    for (int c = 0; c < 8; ++c)
        qf[c] = *(const f16x8*)(Qh + (size_t)(b * SEQ + q0 + lq) * DKV + c * 16 + hi * 8);

    f32x16 o[4] = {};                    // O^T: 4 dv-tiles of 32, q = lq
    float m = -INFINITY, lsum = 0.f;

    const _Float16* Kbase = Kh + (size_t)(b * SEQ + w * 1024) * DKV;
    const _Float16* Vbase = VTh + ((size_t)b * DKV + lq) * SEQ + w * 1024 + hi * 8;

    // ---- prologue: stage K tile 0 into bufA ----
    {
        int4 kreg[8];
        #pragma unroll
        for (int i = 0; i < 8; ++i) {
            int c = l + 64 * i; int row = c >> 4, part = c & 15;
            kreg[i] = *(const int4*)(Kbase + (size_t)row * DKV + part * 8);
        }
        #pragma unroll
        for (int i = 0; i < 8; ++i) {
            int c = l + 64 * i; int row = c >> 4, part = c & 15;
            *(int4*)(bufA + row * 256 + ((part * 16) ^ ((row & 15) << 4))) = kreg[i];
        }
    }

#define BODY(RD, WR, KT) {                                                                 \
        /* V(t) loads -> regs (consumed in PV; covered by QK^T+softmax) */                 \
        f16x8 vreg[8];                                                                     \
        _Pragma("unroll")                                                                  \
        for (int i = 0; i < 8; ++i) {                                                      \
            int dvt = i >> 1, s_ = i & 1;                                                  \
            vreg[i] = *(const f16x8*)(Vbase + (size_t)(dvt * 32) * SEQ +                   \
                                      (KT) * 32 + s_ * 16);                                \
        }                                                                                  \
        /* K(t+1) loads -> regs (ds_written after compute; wrap at end, harmless) */       \
        const int ktn = ((KT) + 1) & 31;                                                   \
        int4 kreg[8];                                                                      \
        _Pragma("unroll")                                                                  \
        for (int i = 0; i < 8; ++i) {                                                      \
            int c = l + 64 * i; int row = c >> 4, part = c & 15;                           \
            kreg[i] = *(const int4*)(Kbase + (size_t)(ktn * 32 + row) * DKV + part * 8);   \
        }                                                                                  \
        /* S^T = K Q^T from LDS buf RD */                                                  \
        f32x16 s = {};                                                                     \
        _Pragma("unroll")                                                                  \
        for (int c = 0; c < 8; ++c) {                                                      \
            f16x8 kf = *(const f16x8*)((RD) + lq * 256 +                                   \
                                       (((2 * c + hi) * 16) ^ ((lq & 15) << 4)));          \
            s = __builtin_amdgcn_mfma_f32_32x32x16_f16(kf, qf[c], s, 0, 0, 0);             \
        }                                                                                  \
        /* in-register online softmax (exp2 domain) */                                     \
        float tm = -INFINITY;                                                              \
        _Pragma("unroll")                                                                  \
        for (int r = 0; r < 16; ++r) tm = fmaxf(tm, s[r]);                                 \
        tm = fmaxf(tm, __shfl_xor(tm, 32));                                                \
        if (__any(tm > m + 8.f)) {                                                         \
            float mnew = fmaxf(m, tm);                                                     \
            float corr = exp2f(m - mnew);                                                  \
            m = mnew; lsum *= corr;                                                        \
            o[0] *= corr; o[1] *= corr; o[2] *= corr; o[3] *= corr;                        \
        }                                                                                  \
        float ts = 0.f;                                                                    \
        _Pragma("unroll")                                                                  \
        for (int r = 0; r < 16; ++r) { s[r] = exp2f(s[r] - m); ts += s[r]; }               \
        ts += __shfl_xor(ts, 32);                                                          \
        lsum += ts;                                                                        \
        /* pack P to f16 */                                                                \
        int wv[8];                                                                         \
        _Pragma("unroll")                                                                  \
        for (int i = 0; i < 8; ++i) wv[i] = pkrtz(s[2 * i], s[2 * i + 1]);                 \
        /* O^T += V^T P, V from prefetched regs */                                         \
        _Pragma("unroll")                                                                  \
        for (int s_ = 0; s_ < 2; ++s_) {                                                   \
            const int base = s_ * 4;                                                       \
            int x0 = __shfl_xor(wv[base + 0], 32);                                         \
            int x1 = __shfl_xor(wv[base + 1], 32);                                         \
            int x2 = __shfl_xor(wv[base + 2], 32);                                         \
            int x3 = __shfl_xor(wv[base + 3], 32);                                         \
            union { int i[4]; f16x8 v; } bu;                                               \
            bu.i[0] = hi ? x2 : wv[base + 0];                                              \
            bu.i[1] = hi ? x3 : wv[base + 1];                                              \
            bu.i[2] = hi ? wv[base + 2] : x0;                                              \
            bu.i[3] = hi ? wv[base + 3] : x1;                                              \
            _Pragma("unroll")                                                              \
            for (int dvt = 0; dvt < 4; ++dvt)                                              \
                o[dvt] = __builtin_amdgcn_mfma_f32_32x32x16_f16(vreg[dvt * 2 + s_], bu.v,  \
                                                                o[dvt], 0, 0, 0);          \
        }                                                                                  \
        /* stage K(t+1) into the other buffer */                                           \
        _Pragma("unroll")                                                                  \
        for (int i = 0; i < 8; ++i) {                                                      \
            int c = l + 64 * i; int row = c >> 4, part = c & 15;                           \
            *(int4*)((WR) + row * 256 + ((part * 16) ^ ((row & 15) << 4))) = kreg[i];      \
        }                                                                                  \
    }

    #pragma unroll 1
    for (int kt2 = 0; kt2 < 16; ++kt2) {
        BODY(bufA, bufB, kt2 * 2)
        BODY(bufB, bufA, kt2 * 2 + 1)
    }
#undef BODY

    // -------- 2-round tree merge of 4 wave partials (same 32 q-cols) --------
    float* obuf  = (float*)lds;                 // 2 snapshots x 4096 f32 = 32 KB
    float* mlbuf = (float*)(lds + 49152);       // 2 snapshots x 64 f32

    __syncthreads();
    if (w == 1 || w == 3) {
        int sb = (w == 3);
        #pragma unroll
        for (int dvt = 0; dvt < 4; ++dvt)
            #pragma unroll
            for (int r = 0; r < 16; ++r)
                obuf[sb * 4096 + (dvt * 16 + r) * 64 + l] = o[dvt][r];
        if (l < 32) {
            mlbuf[sb * 64 + l * 2 + 0] = m;
            mlbuf[sb * 64 + l * 2 + 1] = lsum;
        }
    }
    __syncthreads();
    if (w == 0 || w == 2) {
        int sb = (w == 2);
        float mo  = mlbuf[sb * 64 + lq * 2 + 0];
        float lo_ = mlbuf[sb * 64 + lq * 2 + 1];
        float mn = fmaxf(m, mo);
        float ca = exp2f(m - mn);
        float cb = exp2f(mo - mn);
        m = mn;
        lsum = lsum * ca + lo_ * cb;
        #pragma unroll
        for (int dvt = 0; dvt < 4; ++dvt)
            #pragma unroll
            for (int r = 0; r < 16; ++r)
                o[dvt][r] = o[dvt][r] * ca + obuf[sb * 4096 + (dvt * 16 + r) * 64 + l] * cb;
    }
    __syncthreads();
    if (w == 2) {
        #pragma unroll
        for (int dvt = 0; dvt < 4; ++dvt)
            #pragma unroll
            for (int r = 0; r < 16; ++r)
                obuf[(dvt * 16 + r) * 64 + l] = o[dvt][r];
        if (l < 32) {
            mlbuf[l * 2 + 0] = m;
            mlbuf[l * 2 + 1] = lsum;
        }
    }
    __syncthreads();
    if (w == 0) {
        float mo  = mlbuf[lq * 2 + 0];
        float lo_ = mlbuf[lq * 2 + 1];
        float mn = fmaxf(m, mo);
        float ca = exp2f(m - mn);
        float cb = exp2f(mo - mn);
        float rl = 1.0f / (lsum * ca + lo_ * cb);
        #pragma unroll
        for (int dvt = 0; dvt < 4; ++dvt)
            #pragma unroll
            for (int r = 0; r < 16; ++r)
                o[dvt][r] = (o[dvt][r] * ca + obuf[(dvt * 16 + r) * 64 + l] * cb) * rl;
    }
    __syncthreads();
    // -------- transpose O^T -> row-major via LDS, coalesced store --------
    float* tbuf = (float*)lds;                  // [32][132] f32
    if (w == 0) {
        #pragma unroll
        for (int dvt = 0; dvt < 4; ++dvt)
            #pragma unroll
            for (int r = 0; r < 16; ++r) {
                int dv = dvt * 32 + (r & 3) + 8 * (r >> 2) + 4 * hi;
                tbuf[lq * 132 + dv] = o[dvt][r];
            }
    }
    __syncthreads();
    const size_t obase = (size_t)(b * SEQ + qt * 32) * DKV;
    int row = t >> 3, c0 = (t & 7) * 16;
    #pragma unroll
    for (int i = 0; i < 4; ++i) {
        float4 v = *(const float4*)(tbuf + row * 132 + c0 + i * 4);
        *(float4*)(out + obase + row * 128 + c0 + i * 4) = v;
    }
}

extern "C" void kernel_launch(void* const* d_in, const int* in_sizes, int n_in,
                              void* d_out, int out_size, void* d_ws, size_t ws_size,
                              hipStream_t stream) {
    const float* X  = (const float*)d_in[0];
    const float* Wq = (const float*)d_in[1];
    const float* bq = (const float*)d_in[2];
    const float* Wk = (const float*)d_in[3];
    const float* bk = (const float*)d_in[4];
    const float* Wv = (const float*)d_in[5];
    const float* bv = (const float*)d_in[6];
    float* out = (float*)d_out;

    const size_t nqe = (size_t)NB * SEQ * DKV;            // 2M elements
    _Float16* Qh  = (_Float16*)d_ws;
    _Float16* Kh  = Qh  + nqe;
    _Float16* VTh = Kh  + nqe;
    _Float16* WTh = VTh + nqe;                            // 3*128*1024 f16

    prep_wt<<<(3 * 1024 * 128) / 256, 256, 0, stream>>>(Wq, Wk, Wv, WTh);
    qkv_proj<<<(NB * SEQ / 64) * 3, 256, 0, stream>>>(X, bq, bk, bv, WTh, Qh, Kh, VTh);
    attn_kernel<<<NB * 128, 256, 0, stream>>>(Qh, Kh, VTh, out);
}